// Round 2
// baseline (249.004 us; speedup 1.0000x reference)
//
#include <hip/hip_runtime.h>

// Problem: N=128 rows, C=1000 classes, conf table 50000 x 1000 fp32.
// Identity: sum_k |p[n,k] - I[j,k]| = 2 - 2*p[n,j]  (softmax row sums to 1)
// => out = mean_n( 2*sum_j conf[idx[n],j] - 2*(sum_j e^{o-m} conf_j)/Z )
//
// Single fused kernel, NO workspace, ONE launch:
//   1 block x 1024 threads = 16 waves; each wave owns 8 rows (row = wave + 16*i).
//   Per row: 250 float4 spread as lane + 64*k (k=0..3), whole row in registers.
//   In-wave butterfly reductions (shfl_xor), per-wave accumulator, final LDS
//   reduce across 16 waves, single store to out[0].
// Total traffic: 128*(4KB outputs + 4KB conf) + 512B index ~= 1.03 MB.

#define NROWS 128
#define NCLS  1000
#define NF4   250   // float4 chunks per row

__global__ __launch_bounds__(1024) void fused_loss_kernel(
    const float* __restrict__ outputs,      // [128, 1000]
    const float* __restrict__ conf,         // [50000, 1000]
    const int*   __restrict__ index,        // [128] (int32 on device)
    float* __restrict__ out)                // scalar
{
    const int tid  = threadIdx.x;
    const int lane = tid & 63;
    const int wave = tid >> 6;              // 0..15

    // Prefetch this wave's 8 row indices up front (wave-uniform -> s_load),
    // so the scalar-load latency overlaps the first row's vector loads.
    int idxs[8];
    #pragma unroll
    for (int i = 0; i < 8; ++i) idxs[i] = index[wave + 16 * i];

    float acc = 0.f;

    #pragma unroll
    for (int i = 0; i < 8; ++i) {
        const int row = wave + 16 * i;
        const float* orow = outputs + (size_t)row * NCLS;
        const float* crow = conf + (size_t)idxs[i] * NCLS;

        // Load entire row into registers: lane + 64*k, k=0..3 (250 of 256 valid).
        float4 o[4], c[4];
        #pragma unroll
        for (int k = 0; k < 4; ++k) {
            const int p = lane + 64 * k;
            o[k] = (p < NF4) ? reinterpret_cast<const float4*>(orow)[p]
                             : make_float4(-INFINITY, -INFINITY, -INFINITY, -INFINITY);
        }
        #pragma unroll
        for (int k = 0; k < 4; ++k) {
            const int p = lane + 64 * k;
            c[k] = (p < NF4) ? reinterpret_cast<const float4*>(crow)[p]
                             : make_float4(0.f, 0.f, 0.f, 0.f);
        }

        // ---- wave max (butterfly: all lanes end with row max) ----
        float m = -INFINITY;
        #pragma unroll
        for (int k = 0; k < 4; ++k)
            m = fmaxf(m, fmaxf(fmaxf(o[k].x, o[k].y), fmaxf(o[k].z, o[k].w)));
        #pragma unroll
        for (int off = 1; off < 64; off <<= 1)
            m = fmaxf(m, __shfl_xor(m, off, 64));

        // ---- fused Z / dot / sum-conf ----
        float z = 0.f, dot = 0.f, sc = 0.f;
        #pragma unroll
        for (int k = 0; k < 4; ++k) {
            const float e0 = __expf(o[k].x - m);   // masked lanes: exp(-inf)=0
            const float e1 = __expf(o[k].y - m);
            const float e2 = __expf(o[k].z - m);
            const float e3 = __expf(o[k].w - m);
            z   += (e0 + e1) + (e2 + e3);
            dot += e0 * c[k].x + e1 * c[k].y + e2 * c[k].z + e3 * c[k].w;
            sc  += (c[k].x + c[k].y) + (c[k].z + c[k].w);
        }
        #pragma unroll
        for (int off = 1; off < 64; off <<= 1) {
            z   += __shfl_xor(z,   off, 64);
            dot += __shfl_xor(dot, off, 64);
            sc  += __shfl_xor(sc,  off, 64);
        }

        acc += 2.f * sc - 2.f * dot * __frcp_rn(z);  // identical on all lanes
    }

    // ---- cross-wave reduction, single store ----
    __shared__ float r[16];
    if (lane == 0) r[wave] = acc;
    __syncthreads();
    if (tid == 0) {
        float t = 0.f;
        #pragma unroll
        for (int w = 0; w < 16; ++w) t += r[w];
        out[0] = t * (1.0f / (float)NROWS);
    }
}

extern "C" void kernel_launch(void* const* d_in, const int* in_sizes, int n_in,
                              void* d_out, int out_size, void* d_ws, size_t ws_size,
                              hipStream_t stream) {
    const float* outputs = (const float*)d_in[0];  // [128, 1000]
    const float* conf    = (const float*)d_in[1];  // [50000, 1000]
    const int*   index   = (const int*)d_in[2];    // [128]
    float* out = (float*)d_out;                    // scalar

    // NOTE: d_ws intentionally unused — single kernel, single launch,
    // writes only the 4-byte output.
    fused_loss_kernel<<<1, 1024, 0, stream>>>(outputs, conf, index, out);
}

// Round 3
// 229.386 us; speedup vs baseline: 1.0855x; 1.0855x over previous
//
#include <hip/hip_runtime.h>

// Problem constants (from reference):
//   N = 128 rows, C = 1000 classes, conf table 50000 x 1000 fp32.
// Identity: sum_k |p[n,k] - I[j,k]| = 2 - 2*p[n,j]  (softmax row sums to 1).
// => out = mean_n( 2*sum_j conf[idx[n],j] - 2*(sum_j e^{o-m} conf)/Z )
//
// Structure: 128 blocks (one per row) x 256 threads, each thread owns one
// float4 chunk of the row (250 chunks; threads 250..255 idle). Whole-row
// reductions via wave shuffles + 4-slot LDS. Second tiny kernel reduces the
// 128 per-row values. Timed region is dominated by the harness's ~2x800MB
// poison fills (~229 us at ~6.7 TB/s); our two kernels are ~free beside them
// (verified: single-block fusion instead of this costs +20 us).

#define NROWS 128
#define NCLS  1000

__global__ __launch_bounds__(256) void row_loss_kernel(
    const float* __restrict__ outputs,      // [NROWS, NCLS]
    const float* __restrict__ conf,         // [50000, NCLS]
    const int*   __restrict__ index,        // [NROWS]
    float* __restrict__ ws)                 // [NROWS] per-row results
{
    const int row  = blockIdx.x;
    const int tid  = threadIdx.x;
    const int lane = tid & 63;
    const int wave = tid >> 6;

    __shared__ float redm[4];
    __shared__ float rz[4], rd[4], rs[4];
    __shared__ float bmax;

    // NCLS = 1000 = 250 * 4: threads 0..249 each own one float4; 250..255 idle.
    const int j = tid * 4;
    float4 o = make_float4(-INFINITY, -INFINITY, -INFINITY, -INFINITY);
    if (j < NCLS) {
        o = *reinterpret_cast<const float4*>(outputs + (size_t)row * NCLS + j);
    }

    // ---- block max ----
    float m = fmaxf(fmaxf(o.x, o.y), fmaxf(o.z, o.w));
    #pragma unroll
    for (int off = 32; off > 0; off >>= 1)
        m = fmaxf(m, __shfl_down(m, off, 64));
    if (lane == 0) redm[wave] = m;
    __syncthreads();
    if (tid == 0)
        bmax = fmaxf(fmaxf(redm[0], redm[1]), fmaxf(redm[2], redm[3]));
    __syncthreads();
    m = bmax;

    // ---- fused pass: Z, dot = sum e*conf, sc = sum conf ----
    float z = 0.f, dot = 0.f, sc = 0.f;
    if (j < NCLS) {
        const float* crow = conf + (size_t)index[row] * NCLS;
        const float4 cf = *reinterpret_cast<const float4*>(crow + j);
        const float e0 = __expf(o.x - m);
        const float e1 = __expf(o.y - m);
        const float e2 = __expf(o.z - m);
        const float e3 = __expf(o.w - m);
        z   = (e0 + e1) + (e2 + e3);
        dot = e0 * cf.x + e1 * cf.y + e2 * cf.z + e3 * cf.w;
        sc  = (cf.x + cf.y) + (cf.z + cf.w);
    }
    #pragma unroll
    for (int off = 32; off > 0; off >>= 1) {
        z   += __shfl_down(z,   off, 64);
        dot += __shfl_down(dot, off, 64);
        sc  += __shfl_down(sc,  off, 64);
    }
    if (lane == 0) { rz[wave] = z; rd[wave] = dot; rs[wave] = sc; }
    __syncthreads();
    if (tid == 0) {
        const float Z = (rz[0] + rz[1]) + (rz[2] + rz[3]);
        const float D = (rd[0] + rd[1]) + (rd[2] + rd[3]);
        const float S = (rs[0] + rs[1]) + (rs[2] + rs[3]);
        ws[row] = 2.f * S - 2.f * D / Z;
    }
}

__global__ __launch_bounds__(128) void final_reduce_kernel(
    const float* __restrict__ ws, float* __restrict__ out)
{
    const int tid = threadIdx.x;   // 128 threads = 2 waves
    float v = ws[tid];
    #pragma unroll
    for (int off = 32; off > 0; off >>= 1)
        v += __shfl_down(v, off, 64);
    __shared__ float r[2];
    if ((tid & 63) == 0) r[tid >> 6] = v;
    __syncthreads();
    if (tid == 0) out[0] = (r[0] + r[1]) * (1.0f / (float)NROWS);
}

extern "C" void kernel_launch(void* const* d_in, const int* in_sizes, int n_in,
                              void* d_out, int out_size, void* d_ws, size_t ws_size,
                              hipStream_t stream) {
    const float* outputs = (const float*)d_in[0];  // [128, 1000]
    const float* conf    = (const float*)d_in[1];  // [50000, 1000]
    const int*   index   = (const int*)d_in[2];    // [128]
    float* out = (float*)d_out;                    // scalar
    float* ws  = (float*)d_ws;                     // >= 128 floats

    row_loss_kernel<<<NROWS, 256, 0, stream>>>(outputs, conf, index, ws);
    final_reduce_kernel<<<1, 128, 0, stream>>>(ws, out);
}